// Round 6
// baseline (155.218 us; speedup 1.0000x reference)
//
#include <hip/hip_runtime.h>

#define NF 64

// ws float offsets
#define OFF_NORMG   0          // 2048
#define OFF_NORMP   2048       // 2048
#define OFF_EG      4096       // 131072
#define OFF_EP      135168     // 131072
#define OFF_HA_G    266240     // 131072
#define OFF_HA_P    397312
#define OFF_HB_G    528384
#define OFF_HB_P    659456
#define OFF_NPG     790528     // 8*2048 partial row counts
#define OFF_NPP     806912     // 8*2048 partial col counts
#define OFF_HPART   823296     // 256*64 per-block colsum partials of final h
#define OFF_BAR     839680     // 96 ints (6 barriers x 16 counters)
#define OFF_OBST    841728     // 1048576

static __device__ __forceinline__ float wsum_f(float v) {
#pragma unroll
    for (int off = 1; off < 64; off <<= 1) v += __shfl_xor(v, off, 64);
    return v;
}
static __device__ __forceinline__ int wsum_i(int v) {
#pragma unroll
    for (int off = 1; off < 64; off <<= 1) v += __shfl_xor(v, off, 64);
    return v;
}
static __device__ __forceinline__ float wmax_f(float v) {
#pragma unroll
    for (int off = 1; off < 64; off <<= 1) v = fmaxf(v, __shfl_xor(v, off, 64));
    return v;
}

// grid-wide barrier: 16-way-spread counters, release add + relaxed spin + acquire fence
static __device__ __forceinline__ void gridbar(float* ws, int id, int bid) {
    __syncthreads();
    int* cnt = (int*)(ws + OFF_BAR) + id * 16;
    if (threadIdx.x == 0)
        __hip_atomic_fetch_add(&cnt[bid & 15], 1, __ATOMIC_RELEASE, __HIP_MEMORY_SCOPE_AGENT);
    if (threadIdx.x < 64) {
        int lane = threadIdx.x;
        int s;
        do {
            int v = (lane < 16) ? __hip_atomic_load(&cnt[lane], __ATOMIC_RELAXED,
                                                    __HIP_MEMORY_SCOPE_AGENT) : 0;
            s = wsum_i(v);
            if (s < 256) __builtin_amdgcn_s_sleep(2);
        } while (s < 256);
        __builtin_amdgcn_fence(__ATOMIC_ACQUIRE, "agent");
    }
    __syncthreads();
}

__global__ __launch_bounds__(128) void k_zero(float* __restrict__ ws) {
    int t = threadIdx.x;
    if (t < 96) ((int*)(ws + OFF_BAR))[t] = 0;
}

__global__ __launch_bounds__(1024, 4) void k_mega(
        const float* __restrict__ obs, float* __restrict__ ws,
        const float* __restrict__ Wi_g, const float* __restrict__ Wi_p,
        const float* __restrict__ Wee_g, const float* __restrict__ Wef_g,
        const float* __restrict__ Wee_p, const float* __restrict__ Wef_p,
        const float* __restrict__ Wm_g, const float* __restrict__ Wu_g,
        const float* __restrict__ Wm_p, const float* __restrict__ Wu_p,
        const float* __restrict__ Wpg, const float* __restrict__ Wpp,
        const float* __restrict__ Wro, const float* __restrict__ bro,
        float* __restrict__ out) {
    __shared__ __align__(16) float smem[32768];   // 128 KB
    int bid = blockIdx.x;
    int t = threadIdx.x, lane = t & 63, w = t >> 6;   // 16 waves

    // ---------------- P0: transpose tile + partial nonzero counts ----------------
    {
        int b = bid >> 6, tg = (bid >> 3) & 7, tp = bid & 7;
        int g0 = tg * 64, p0 = tp * 64;
        const float* src = obs + ((size_t)b * 512 + g0) * 512 + p0;
        float* tile = smem;            // 64*65
        float* colc = smem + 4224;     // 16*64
        float cc = 0.f;
#pragma unroll
        for (int i = 0; i < 4; ++i) {
            int r = w + 16 * i;
            float v = src[(size_t)r * 512 + lane];
            tile[r * 65 + lane] = v;
            float nz = (v != 0.f) ? 1.f : 0.f;
            cc += nz;
            float rs = wsum_f(nz);
            if (lane == 0) ws[OFF_NPG + tp * 2048 + b * 512 + g0 + r] = rs;
        }
        colc[w * 64 + lane] = cc;
        __syncthreads();
        if (w == 0) {
            float s = 0.f;
#pragma unroll
            for (int j = 0; j < 16; ++j) s += colc[j * 64 + lane];
            ws[OFF_NPP + tg * 2048 + b * 512 + p0 + lane] = s;
        }
        float* dst = ws + OFF_OBST + ((size_t)b * 512 + p0) * 512 + g0;
#pragma unroll
        for (int i = 0; i < 4; ++i) {
            int pr = w + 16 * i;
            dst[(size_t)pr * 512 + lane] = tile[lane * 65 + pr];
        }
    }
    gridbar(ws, 0, bid);

    // ---------------- P1: reduce partials -> norms ----------------
    {
        int idx = bid * 16 + w;            // 0..4095
        int side = idx >> 11, lr = idx & 2047;
        const float* part = ws + (side ? OFF_NPP : OFF_NPG) + lr;
        float v = (lane < 8) ? part[lane * 2048] : 0.f;
        v = wsum_f(v);
        if (lane == 0) ws[(side ? OFF_NORMP : OFF_NORMG) + lr] = v;
    }
    gridbar(ws, 1, bid);

    // ---------------- P2: max, U, S, init h & e (16 rows/block) ----------------
    {
        int side = bid >> 7, lr0 = (bid & 127) * 16, b = lr0 >> 9;
        const float* normown = ws + (side ? OFF_NORMP : OFF_NORMG);
        const float* normopp = ws + (side ? OFF_NORMG : OFF_NORMP) + b * 512;
        float m = fmaxf(normown[t], normown[t + 1024]);
        m = wmax_f(m);
        if (lane == 0) smem[w] = m;
        __syncthreads();
        if (t == 0) {
            float mm = smem[0];
#pragma unroll
            for (int j = 1; j < 16; ++j) mm = fmaxf(mm, smem[j]);
            smem[16] = fmaxf(mm, 1.f);
        }
        const float* Wee = side ? Wee_p : Wee_g;
        const float* Wef = side ? Wef_p : Wef_g;
        if (w == 1) {
            float u = 0.f;
#pragma unroll
            for (int e = 0; e < 63; ++e) u += fmaxf(Wee[e], 0.f) * Wef[e * 64 + lane];
            smem[64 + lane] = u;
        }
        int lr = lr0 + w;
        const float* arow = (side ? ws + OFF_OBST : obs) + (size_t)lr * 512;
        float s = 0.f;
#pragma unroll
        for (int j = 0; j < 8; ++j) {
            float v = arow[lane + 64 * j];
            if (v != 0.f) s += normopp[lane + 64 * j];
        }
        s = wsum_f(s) * (1.f / 512.f);
        __syncthreads();
        float maxnf = smem[16];
        float U = smem[64 + lane];
        float norm = normown[lr];
        float nf1 = norm > 0.f ? norm : 1.f;
        const float* Wi = side ? Wi_p : Wi_g;
        float h = fmaxf(norm * (1.f / 512.f) * Wi[lane], 0.f);
        ws[(side ? OFF_HA_P : OFF_HA_G) + (size_t)lr * 64 + lane] = h;
        float A = s / nf1;
        float C = norm / maxnf;
        float e = fmaxf(A * U + C * Wef[63 * 64 + lane], 0.f);
        ws[(side ? OFF_EP : OFF_EG) + (size_t)lr * 64 + lane] = e;
    }
    gridbar(ws, 2, bid);

    // ---------------- P3: three MPNN layers ----------------
    int side = bid >> 7, lr0 = (bid & 127) * 16, b = lr0 >> 9;
    float* SA = smem;            // 16384: h-half / weights
    float* SB = smem + 16384;    // 8192:  adj tile 16x512
    float* SG = smem + 24576;    // 4096:  split-K partials [4][16][64]
    float* SR = smem + 28672;    // 4096:  rowbuf agg/e/hself/m
    int r4 = w & 3, ksub = w >> 2;

    for (int L = 0; L < 3; ++L) {
        int hinG = (L & 1) ? OFF_HB_G : OFF_HA_G;
        int hinP = (L & 1) ? OFF_HB_P : OFF_HA_P;
        int houtG = (L & 1) ? OFF_HA_G : OFF_HB_G;
        int houtP = (L & 1) ? OFF_HA_P : OFF_HB_P;
        const float* adj = (side ? ws + OFF_OBST : obs) + (size_t)lr0 * 512;
        const float* hopp = ws + (side ? hinG : hinP) + (size_t)b * 32768;
        const float* hself = ws + (side ? hinP : hinG) + (size_t)lr0 * 64;
        const float* e_b = ws + (side ? OFF_EP : OFF_EG) + (size_t)lr0 * 64;
        const float* nrm = ws + (side ? OFF_NORMP : OFF_NORMG) + lr0;
        const float* Wm = (side ? Wm_p : Wm_g) + L * 8192;
        const float* Wu = (side ? Wu_p : Wu_g) + L * 8192;
        float* hout = ws + (side ? houtP : houtG) + (size_t)lr0 * 64;

        {   // stage adj 16x512 (coalesced)
            float4* dst = (float4*)SB;
#pragma unroll
            for (int i = 0; i < 2; ++i) {
                int idx = t + 1024 * i;
                int r = idx >> 7, c4 = idx & 127;
                dst[idx] = *(const float4*)(adj + (size_t)r * 512 + c4 * 4);
            }
        }
        float acc0 = 0.f, acc1 = 0.f, acc2 = 0.f, acc3 = 0.f;
#pragma unroll
        for (int half = 0; half < 2; ++half) {
            {   // stage h half 256x64 (coalesced)
                const float4* src = (const float4*)(hopp + half * 16384);
                float4* dst = (float4*)SA;
#pragma unroll
                for (int i = 0; i < 4; ++i) dst[t + 1024 * i] = src[t + 1024 * i];
            }
            __syncthreads();
            const float* hc = SA + lane;
            int kb = half * 256 + ksub * 64;   // within adj row
            int klds = ksub * 64;              // within h half
#pragma unroll 4
            for (int k4 = 0; k4 < 16; ++k4) {
                float4 a0 = *(const float4*)(SB + (r4 + 0) * 512 + kb + k4 * 4);
                float4 a1 = *(const float4*)(SB + (r4 + 4) * 512 + kb + k4 * 4);
                float4 a2 = *(const float4*)(SB + (r4 + 8) * 512 + kb + k4 * 4);
                float4 a3 = *(const float4*)(SB + (r4 + 12) * 512 + kb + k4 * 4);
#pragma unroll
                for (int j = 0; j < 4; ++j) {
                    float hv = hc[(size_t)(klds + k4 * 4 + j) * 64];
                    acc0 += ((const float*)&a0)[j] * hv;
                    acc1 += ((const float*)&a1)[j] * hv;
                    acc2 += ((const float*)&a2)[j] * hv;
                    acc3 += ((const float*)&a3)[j] * hv;
                }
            }
            __syncthreads();
        }
        SG[ksub * 1024 + (r4 + 0) * 64 + lane] = acc0;
        SG[ksub * 1024 + (r4 + 4) * 64 + lane] = acc1;
        SG[ksub * 1024 + (r4 + 8) * 64 + lane] = acc2;
        SG[ksub * 1024 + (r4 + 12) * 64 + lane] = acc3;
        __syncthreads();
        {   // combine split-K + load e, h_self into SR
            float rcp = 1.f / fmaxf(nrm[w], 1.f);
            float agg = (SG[w * 64 + lane] + SG[1024 + w * 64 + lane] +
                         SG[2048 + w * 64 + lane] + SG[3072 + w * 64 + lane]) * rcp;
            SR[w * 64 + lane] = agg;
            SR[1024 + w * 64 + lane] = e_b[(size_t)w * 64 + lane];
            SR[2048 + w * 64 + lane] = hself[(size_t)w * 64 + lane];
        }
        {   // stage weights Wm,Wu into SA (coalesced)
            const float4* s1 = (const float4*)Wm;
            const float4* s2 = (const float4*)Wu;
            float4* d = (float4*)SA;
#pragma unroll
            for (int i = 0; i < 2; ++i) {
                d[t + 1024 * i] = s1[t + 1024 * i];
                d[2048 + t + 1024 * i] = s2[t + 1024 * i];
            }
        }
        __syncthreads();
        // msg: thread (r=w, f=lane)
        float mv = 0.f;
        {
            const float4* ar = (const float4*)(SR + w * 64);
            const float4* er = (const float4*)(SR + 1024 + w * 64);
#pragma unroll 4
            for (int k4 = 0; k4 < 16; ++k4) {
                float4 a = ar[k4], e4 = er[k4];
#pragma unroll
                for (int j = 0; j < 4; ++j) {
                    mv += ((const float*)&a)[j] * SA[(k4 * 4 + j) * 64 + lane];
                    mv += ((const float*)&e4)[j] * SA[(64 + k4 * 4 + j) * 64 + lane];
                }
            }
            mv = fmaxf(mv, 0.f);
        }
        __syncthreads();
        SR[3072 + w * 64 + lane] = mv;
        __syncthreads();
        // upd
        float hv = 0.f;
        {
            const float4* hr = (const float4*)(SR + 2048 + w * 64);
            const float4* mr = (const float4*)(SR + 3072 + w * 64);
#pragma unroll 4
            for (int k4 = 0; k4 < 16; ++k4) {
                float4 hh = hr[k4], m4 = mr[k4];
#pragma unroll
                for (int j = 0; j < 4; ++j) {
                    hv += ((const float*)&hh)[j] * SA[8192 + (k4 * 4 + j) * 64 + lane];
                    hv += ((const float*)&m4)[j] * SA[8192 + (64 + k4 * 4 + j) * 64 + lane];
                }
            }
            hv = fmaxf(hv, 0.f);
            hout[(size_t)w * 64 + lane] = hv;
        }
        if (L == 2) {   // per-block colsum partial of final h
            __syncthreads();
            SG[w * 64 + lane] = hv;
            __syncthreads();
            if (w == 0) {
                float s = 0.f;
#pragma unroll
                for (int j = 0; j < 16; ++j) s += SG[j * 64 + lane];
                ws[OFF_HPART + bid * 64 + lane] = s;
            }
        }
        gridbar(ws, 3 + L, bid);
    }

    // ---------------- P7: pool + readout (8 outputs/block) ----------------
    {
        int row0 = bid * 8, bb = row0 >> 9;
        if (t < 128) {
            int sideq = t >> 6, k = t & 63;
            const float* hp = ws + OFF_HPART + (size_t)(sideq * 128 + bb * 32) * 64 + k;
            float s = 0.f;
#pragma unroll
            for (int j = 0; j < 32; ++j) s += hp[j * 64];
            smem[t] = s;
        }
        __syncthreads();
        if (t < 64) {
            float vg = 0.f, vp = 0.f;
#pragma unroll 4
            for (int k = 0; k < 64; ++k) {
                vg += (smem[k] * (1.f / 512.f)) * Wpg[k * 64 + t];
                vp += (smem[64 + k] * (1.f / 512.f)) * Wpp[k * 64 + t];
            }
            float hpv = fmaxf(vg + vp, 0.f);
            smem[128 + t] = hpv * Wro[t];
        }
        __syncthreads();
        if (t < 64) {
            float c = wsum_f(smem[128 + t]);
            if (t == 0) smem[192] = c + bro[0];
        }
        __syncthreads();
        if (t < 512) {
            int r = t >> 6;
            int idx = row0 + r;
            float v = ws[OFF_HB_G + (size_t)idx * 64 + lane] * Wro[64 + lane];
            v = wsum_f(v);
            if (lane == 0) out[idx] = smem[192] + v;
        }
    }
}

extern "C" void kernel_launch(void* const* d_in, const int* in_sizes, int n_in,
                              void* d_out, int out_size, void* d_ws, size_t ws_size,
                              hipStream_t stream) {
    const float* obs   = (const float*)d_in[0];
    const float* Wi_g  = (const float*)d_in[1];
    const float* Wi_p  = (const float*)d_in[2];
    const float* Wee_g = (const float*)d_in[3];
    const float* Wef_g = (const float*)d_in[4];
    const float* Wee_p = (const float*)d_in[5];
    const float* Wef_p = (const float*)d_in[6];
    const float* Wm_g  = (const float*)d_in[7];
    const float* Wu_g  = (const float*)d_in[8];
    const float* Wm_p  = (const float*)d_in[9];
    const float* Wu_p  = (const float*)d_in[10];
    const float* Wpg   = (const float*)d_in[11];
    const float* Wpp   = (const float*)d_in[12];
    const float* Wro   = (const float*)d_in[13];
    const float* bro   = (const float*)d_in[14];
    float* ws  = (float*)d_ws;
    float* out = (float*)d_out;

    k_zero<<<1, 128, 0, stream>>>(ws);
    k_mega<<<256, 1024, 0, stream>>>(obs, ws, Wi_g, Wi_p, Wee_g, Wef_g, Wee_p, Wef_p,
                                     Wm_g, Wu_g, Wm_p, Wu_p, Wpg, Wpp, Wro, bro, out);
}

// Round 7
// 132.791 us; speedup vs baseline: 1.1689x; 1.1689x over previous
//
#include <hip/hip_runtime.h>

#define NF 64

// ws float offsets (ws = 256 MB)
#define OFF_NORMG   0          // 2048
#define OFF_NORMP   2048       // 2048
#define OFF_SG      4096       // 2048
#define OFF_SP      6144       // 2048
#define OFF_MAXG    8192       // 1 (float)
#define OFF_MAXP    8193       // 1 (float)
#define OFF_U       8194       // 128
#define OFF_HSUMG   8322       // 256
#define OFF_HSUMP   8578       // 256
#define OFF_C1      8834       // 4
#define OFF_NPG     9216       // 8*2048 partial row counts (g side)
#define OFF_NPP     25600      // 8*2048 partial col counts (p side)
#define OFF_HA_G    41984      // 131072
#define OFF_HA_P    173056
#define OFF_HB_G    304128
#define OFF_HB_P    435200
#define OFF_EG      566272
#define OFF_EP      697344
#define OFF_OBST    828416     // 1048576 floats
#define OFF_PART    1900544    // [slice8][side2][f64][row2048] = 2097152 floats

static __device__ __forceinline__ float wave_sum(float v) {
    for (int off = 32; off; off >>= 1) v += __shfl_down(v, off, 64);
    return v;
}
static __device__ __forceinline__ float wave_max(float v) {
    for (int off = 32; off; off >>= 1) v = fmaxf(v, __shfl_down(v, off, 64));
    return v;
}

// ---------------- K1: transpose obs -> obsT, partial row/col nonzero counts ----------------
__global__ __launch_bounds__(256) void k_prep(const float* __restrict__ obs,
                                              float* __restrict__ ws) {
    __shared__ float tile[64][65];
    __shared__ float cc[4][64];
    int b = blockIdx.y, t = threadIdx.x;
    int tg = blockIdx.x >> 3, tp = blockIdx.x & 7;
    int g0 = tg * 64, p0 = tp * 64;
    int c = t & 63, r0 = t >> 6;
    const float* src = obs + ((size_t)b * 512 + g0) * 512 + p0;
    float colcnt = 0.f;
#pragma unroll
    for (int i = 0; i < 16; ++i) {
        int r = r0 + 4 * i;
        float v = src[(size_t)r * 512 + c];
        tile[r][c] = v;
        float nz = (v != 0.f) ? 1.f : 0.f;
        colcnt += nz;
        nz = wave_sum(nz);
        if (c == 0) ws[OFF_NPG + tp * 2048 + b * 512 + g0 + r] = nz;
    }
    cc[r0][c] = colcnt;
    __syncthreads();
    if (r0 == 0)
        ws[OFF_NPP + tg * 2048 + b * 512 + p0 + c] =
            cc[0][c] + cc[1][c] + cc[2][c] + cc[3][c];
    float* dst = ws + OFF_OBST + ((size_t)b * 512 + p0) * 512 + g0;
#pragma unroll
    for (int i = 0; i < 16; ++i) {
        int pr = r0 + 4 * i;
        dst[(size_t)pr * 512 + c] = tile[c][pr];
    }
}

// ---------------- K1b: reduce partials -> norms ----------------
__global__ __launch_bounds__(256) void k_norm(float* __restrict__ ws) {
    int idx = blockIdx.x * 256 + threadIdx.x;   // 0..4095
    int side = idx >> 11, lr = idx & 2047;
    const float* part = ws + (side ? OFF_NPP : OFF_NPG) + lr;
    float s = 0.f;
#pragma unroll
    for (int j = 0; j < 8; ++j) s += part[j * 2048];
    ws[(side ? OFF_NORMP : OFF_NORMG) + lr] = s;
}

// ---------------- K2: S sums; block 1024 does norm-maxes + U precompute ----------------
__global__ __launch_bounds__(256) void k_s(const float* __restrict__ obs,
                                           float* __restrict__ ws,
                                           const float* __restrict__ Wee_g,
                                           const float* __restrict__ Wef_g,
                                           const float* __restrict__ Wee_p,
                                           const float* __restrict__ Wef_p) {
    int bid = blockIdx.x;
    if (bid == 1024) {
        __shared__ float redg[4], redp[4];
        int t = threadIdx.x, lane = t & 63, w = t >> 6;
        float mg = 0.f, mp = 0.f;
        for (int k = t; k < 2048; k += 256) {
            mg = fmaxf(mg, ws[OFF_NORMG + k]);
            mp = fmaxf(mp, ws[OFF_NORMP + k]);
        }
        mg = wave_max(mg);
        mp = wave_max(mp);
        if (lane == 0) { redg[w] = mg; redp[w] = mp; }
        __syncthreads();
        if (t == 0) {
            ws[OFF_MAXG] = fmaxf(fmaxf(redg[0], redg[1]), fmaxf(redg[2], redg[3]));
            ws[OFF_MAXP] = fmaxf(fmaxf(redp[0], redp[1]), fmaxf(redp[2], redp[3]));
        }
        if (t < 128) {
            int side = t >> 6, f = t & 63;
            const float* Wee = side ? Wee_p : Wee_g;
            const float* Wef = side ? Wef_p : Wef_g;
            float u = 0.f;
#pragma unroll
            for (int e = 0; e < 63; ++e) u += fmaxf(Wee[e], 0.f) * Wef[e * 64 + f];
            ws[OFF_U + t] = u;
        }
        return;
    }
    int t = threadIdx.x, w = t >> 6, lane = t & 63;
    int row = bid * 4 + w;          // 0..4095
    int side = row >> 11;
    int lr = row & 2047;
    int b = lr >> 9;
    const float* arow = side ? (ws + OFF_OBST + (size_t)lr * 512)
                             : (obs + (size_t)lr * 512);
    const float* wnorm = ws + (side ? OFF_NORMG : OFF_NORMP) + b * 512;
    float s = 0.f;
#pragma unroll
    for (int k = 0; k < 8; ++k) {
        int p = lane + 64 * k;
        float v = arow[p];
        if (v != 0.f) s += wnorm[p];
    }
    s = wave_sum(s) * (1.f / 512.f);
    if (lane == 0) ws[(side ? OFF_SP : OFF_SG) + lr] = s;
}

// ---------------- K3: init h and e (edge embedding collapsed) ----------------
__global__ __launch_bounds__(256) void k_init(const float* __restrict__ Wi_g,
                                              const float* __restrict__ Wi_p,
                                              const float* __restrict__ Wef_g,
                                              const float* __restrict__ Wef_p,
                                              float* __restrict__ ws) {
    int idx = blockIdx.x * 256 + threadIdx.x;  // 0..262143
    int row = idx >> 6, f = idx & 63;
    int side = row >> 11, lr = row & 2047;
    float norm = ws[(side ? OFF_NORMP : OFF_NORMG) + lr];
    float nf1 = norm > 0.f ? norm : 1.f;
    float nf = norm * (1.f / 512.f);
    const float* Wi = side ? Wi_p : Wi_g;
    float h = fmaxf(nf * Wi[f], 0.f);
    ws[(side ? OFF_HA_P : OFF_HA_G) + (size_t)lr * 64 + f] = h;
    float A = ws[(side ? OFF_SP : OFF_SG) + lr] / nf1;
    float maxnf = fmaxf(ws[side ? OFF_MAXP : OFF_MAXG], 1.f);
    float C = norm / maxnf;
    float U = ws[OFF_U + side * 64 + f];
    const float* Wef = side ? Wef_p : Wef_g;
    float e = fmaxf(A * U + C * Wef[63 * 64 + f], 0.f);
    ws[(side ? OFF_EP : OFF_EG) + (size_t)lr * 64 + f] = e;
}

// ---------------- K4a: aggregation. 512 blocks x 256 threads ----------------
// lane = row (64-row tile); per-lane stream = adjT column (coalesced global b32);
// h operand is wave-uniform -> SGPR via s_load; NO LDS, NO syncthreads.
// block = slice(8) x side(2) x tile(32); k-slice of 64.
__global__ __launch_bounds__(256) void k_agg(const float* __restrict__ obs,
                                             float* __restrict__ ws,
                                             int hin_g, int hin_p) {
    int bid = blockIdx.x;
    int slice = bid >> 6, side = (bid >> 5) & 1, tile = bid & 31;
    int r0 = tile * 64;                 // row within side (0..2047)
    int b = r0 >> 9, rs = r0 & 511;
    int k0 = slice * 64;
    int t = threadIdx.x, lane = t & 63;
    int w = __builtin_amdgcn_readfirstlane(t >> 6);
    int f0 = w * 16;
    // adjT[k][row]: g-side -> obsT, p-side -> obs
    const float* at = (side ? obs : ws + OFF_OBST)
                      + (size_t)b * 262144 + (size_t)k0 * 512 + rs + lane;
    const float* hb = ws + (side ? hin_g : hin_p)
                      + (size_t)b * 32768 + (size_t)k0 * 64 + f0;   // uniform
    float acc[16];
#pragma unroll
    for (int j = 0; j < 16; ++j) acc[j] = 0.f;
#pragma unroll 4
    for (int k = 0; k < 64; ++k) {
        float a = at[(size_t)k * 512];          // per-lane coalesced b32
#pragma unroll
        for (int j = 0; j < 16; ++j)            // hb[..] uniform -> s_load + v_fmac(v,s,v)
            acc[j] = fmaf(a, hb[k * 64 + j], acc[j]);
    }
    // partial store: PART[slice][side][f][row] -> coalesced along rows
    float* pp = ws + OFF_PART + ((size_t)(slice * 2 + side) * 64 + f0) * 2048 + r0 + lane;
#pragma unroll
    for (int j = 0; j < 16; ++j) pp[(size_t)j * 2048] = acc[j];
}

// ---------------- K4b: combine + MLP. 256 blocks x 256 threads ----------------
// block = side x tile(16 rows). lane = f; wave handles 4 rows in registers.
// W streams: per-lane coalesced global vloads; row operands: s_load (global) or
// uniform b128 from a tiny LDS buffer (agg, m only).
__global__ __launch_bounds__(256) void k_mlp(float* __restrict__ ws,
                                             const float* __restrict__ Wmsg_g,
                                             const float* __restrict__ Wupd_g,
                                             const float* __restrict__ Wmsg_p,
                                             const float* __restrict__ Wupd_p,
                                             int layer, int hin_g, int hin_p,
                                             int hout_g, int hout_p) {
    __shared__ float agglds[16][NF];
    __shared__ float mlds[16][NF];
    int bid = blockIdx.x, side = bid >> 7, tile = bid & 127;
    int R0 = tile * 16;                 // row within side
    int t = threadIdx.x, lane = t & 63;

    {   // combine 8 split-K partials, normalize -> agglds
        int r = t & 15, fq = t >> 4;    // f = fq*4..fq*4+3
        float rcp = 1.f / fmaxf(ws[(side ? OFF_NORMP : OFF_NORMG) + R0 + r], 1.f);
#pragma unroll
        for (int j = 0; j < 4; ++j) {
            int f = fq * 4 + j;
            const float* pp = ws + OFF_PART + ((size_t)side * 64 + f) * 2048 + R0 + r;
            float s = 0.f;
#pragma unroll
            for (int sl = 0; sl < 8; ++sl) s += pp[(size_t)sl * 262144];
            agglds[r][f] = s * rcp;
        }
    }
    __syncthreads();

    int w = __builtin_amdgcn_readfirstlane(t >> 6);   // rows w*4 .. w*4+3
    const float* Wm = (side ? Wmsg_p : Wmsg_g) + layer * 8192;
    const float* Wu = (side ? Wupd_p : Wupd_g) + layer * 8192;
    const float* e0 = ws + (side ? OFF_EP : OFF_EG) + (size_t)R0 * 64 + w * 4 * 64;
    const float* h0 = ws + (side ? hin_p : hin_g) + (size_t)R0 * 64 + w * 4 * 64;
    float* hout = ws + (side ? hout_p : hout_g) + (size_t)R0 * 64 + w * 4 * 64;

    // ---- msg = relu([agg, e] @ Wm) ----
    float m0 = 0.f, m1 = 0.f, m2 = 0.f, m3 = 0.f;
#pragma unroll 4
    for (int k4 = 0; k4 < 16; ++k4) {
        float4 a0 = *(const float4*)&agglds[w * 4 + 0][k4 * 4];
        float4 a1 = *(const float4*)&agglds[w * 4 + 1][k4 * 4];
        float4 a2 = *(const float4*)&agglds[w * 4 + 2][k4 * 4];
        float4 a3 = *(const float4*)&agglds[w * 4 + 3][k4 * 4];
#pragma unroll
        for (int j = 0; j < 4; ++j) {
            float wv = Wm[(k4 * 4 + j) * 64 + lane];      // coalesced vload
            m0 = fmaf(((const float*)&a0)[j], wv, m0);
            m1 = fmaf(((const float*)&a1)[j], wv, m1);
            m2 = fmaf(((const float*)&a2)[j], wv, m2);
            m3 = fmaf(((const float*)&a3)[j], wv, m3);
        }
    }
#pragma unroll 4
    for (int k4 = 0; k4 < 16; ++k4) {
#pragma unroll
        for (int j = 0; j < 4; ++j) {
            int k = k4 * 4 + j;
            float wv = Wm[(64 + k) * 64 + lane];          // coalesced vload
            m0 = fmaf(e0[k], wv, m0);                     // e0[..] uniform -> s_load
            m1 = fmaf(e0[64 + k], wv, m1);
            m2 = fmaf(e0[128 + k], wv, m2);
            m3 = fmaf(e0[192 + k], wv, m3);
        }
    }
    mlds[w * 4 + 0][lane] = fmaxf(m0, 0.f);
    mlds[w * 4 + 1][lane] = fmaxf(m1, 0.f);
    mlds[w * 4 + 2][lane] = fmaxf(m2, 0.f);
    mlds[w * 4 + 3][lane] = fmaxf(m3, 0.f);
    __syncthreads();

    // ---- h_new = relu([h, m] @ Wu) ----
    float h0a = 0.f, h1a = 0.f, h2a = 0.f, h3a = 0.f;
#pragma unroll 4
    for (int k4 = 0; k4 < 16; ++k4) {
#pragma unroll
        for (int j = 0; j < 4; ++j) {
            int k = k4 * 4 + j;
            float wv = Wu[k * 64 + lane];
            h0a = fmaf(h0[k], wv, h0a);                   // h0[..] uniform -> s_load
            h1a = fmaf(h0[64 + k], wv, h1a);
            h2a = fmaf(h0[128 + k], wv, h2a);
            h3a = fmaf(h0[192 + k], wv, h3a);
        }
    }
#pragma unroll 4
    for (int k4 = 0; k4 < 16; ++k4) {
        float4 q0 = *(const float4*)&mlds[w * 4 + 0][k4 * 4];
        float4 q1 = *(const float4*)&mlds[w * 4 + 1][k4 * 4];
        float4 q2 = *(const float4*)&mlds[w * 4 + 2][k4 * 4];
        float4 q3 = *(const float4*)&mlds[w * 4 + 3][k4 * 4];
#pragma unroll
        for (int j = 0; j < 4; ++j) {
            float wv = Wu[(64 + k4 * 4 + j) * 64 + lane];
            h0a = fmaf(((const float*)&q0)[j], wv, h0a);
            h1a = fmaf(((const float*)&q1)[j], wv, h1a);
            h2a = fmaf(((const float*)&q2)[j], wv, h2a);
            h3a = fmaf(((const float*)&q3)[j], wv, h3a);
        }
    }
    hout[lane]       = fmaxf(h0a, 0.f);
    hout[64 + lane]  = fmaxf(h1a, 0.f);
    hout[128 + lane] = fmaxf(h2a, 0.f);
    hout[192 + lane] = fmaxf(h3a, 0.f);
}

// ---------------- K4c: column sums of final h ----------------
__global__ __launch_bounds__(256) void k_hsum(float* __restrict__ ws) {
    __shared__ float red[4][NF];
    int bid = blockIdx.x, side = bid >> 2, b = bid & 3;
    int t = threadIdx.x, f = t & 63, w = t >> 6;
    const float* h = ws + (side ? OFF_HB_P : OFF_HB_G) + (size_t)b * 32768;
    float s = 0.f;
    for (int r = w; r < 512; r += 4) s += h[(size_t)r * 64 + f];
    red[w][f] = s;
    __syncthreads();
    if (w == 0)
        ws[(side ? OFF_HSUMP : OFF_HSUMG) + b * 64 + f] =
            red[0][f] + red[1][f] + red[2][f] + red[3][f];
}

// ---------------- K5: pooled readout constant c1[b] ----------------
__global__ __launch_bounds__(256) void k_pool(const float* __restrict__ Wpg,
                                              const float* __restrict__ Wpp,
                                              const float* __restrict__ Wro,
                                              const float* __restrict__ bro,
                                              float* __restrict__ ws) {
    int t = threadIdx.x;          // 256 = B*64
    int b = t >> 6, f = t & 63;
    const float* hsg = ws + OFF_HSUMG + b * 64;
    const float* hsp = ws + OFF_HSUMP + b * 64;
    float vg = 0.f, vp = 0.f;
#pragma unroll
    for (int k = 0; k < 64; ++k) {
        vg += (hsg[k] * (1.f / 512.f)) * Wpg[k * 64 + f];
        vp += (hsp[k] * (1.f / 512.f)) * Wpp[k * 64 + f];
    }
    float hp = fmaxf(vg + vp, 0.f);
    float c = wave_sum(hp * Wro[f]);
    if (f == 0) ws[OFF_C1 + b] = c + bro[0];
}

// ---------------- K6: out[b,g] = c1[b] + h_g[b,g,:] . Wro[64:128] ----------------
__global__ __launch_bounds__(256) void k_out(const float* __restrict__ Wro,
                                             const float* __restrict__ ws,
                                             float* __restrict__ out) {
    int idx = blockIdx.x * 256 + threadIdx.x;   // 0..2047
    int b = idx >> 9;
    const float4* hrow = (const float4*)(ws + OFF_HB_G + (size_t)idx * 64);
    float s = 0.f;
#pragma unroll
    for (int k4 = 0; k4 < 16; ++k4) {
        float4 h4 = hrow[k4];
        s += h4.x * Wro[64 + k4 * 4 + 0];
        s += h4.y * Wro[64 + k4 * 4 + 1];
        s += h4.z * Wro[64 + k4 * 4 + 2];
        s += h4.w * Wro[64 + k4 * 4 + 3];
    }
    out[idx] = ws[OFF_C1 + b] + s;
}

extern "C" void kernel_launch(void* const* d_in, const int* in_sizes, int n_in,
                              void* d_out, int out_size, void* d_ws, size_t ws_size,
                              hipStream_t stream) {
    const float* obs   = (const float*)d_in[0];
    const float* Wi_g  = (const float*)d_in[1];
    const float* Wi_p  = (const float*)d_in[2];
    const float* Wee_g = (const float*)d_in[3];
    const float* Wef_g = (const float*)d_in[4];
    const float* Wee_p = (const float*)d_in[5];
    const float* Wef_p = (const float*)d_in[6];
    const float* Wm_g  = (const float*)d_in[7];
    const float* Wu_g  = (const float*)d_in[8];
    const float* Wm_p  = (const float*)d_in[9];
    const float* Wu_p  = (const float*)d_in[10];
    const float* Wpg   = (const float*)d_in[11];
    const float* Wpp   = (const float*)d_in[12];
    const float* Wro   = (const float*)d_in[13];
    const float* bro   = (const float*)d_in[14];
    float* ws  = (float*)d_ws;
    float* out = (float*)d_out;

    k_prep<<<dim3(64, 4), 256, 0, stream>>>(obs, ws);
    k_norm<<<16, 256, 0, stream>>>(ws);
    k_s<<<1025, 256, 0, stream>>>(obs, ws, Wee_g, Wef_g, Wee_p, Wef_p);
    k_init<<<1024, 256, 0, stream>>>(Wi_g, Wi_p, Wef_g, Wef_p, ws);

    // layer 0: HA -> HB
    k_agg<<<512, 256, 0, stream>>>(obs, ws, OFF_HA_G, OFF_HA_P);
    k_mlp<<<256, 256, 0, stream>>>(ws, Wm_g, Wu_g, Wm_p, Wu_p, 0,
                                   OFF_HA_G, OFF_HA_P, OFF_HB_G, OFF_HB_P);
    // layer 1: HB -> HA
    k_agg<<<512, 256, 0, stream>>>(obs, ws, OFF_HB_G, OFF_HB_P);
    k_mlp<<<256, 256, 0, stream>>>(ws, Wm_g, Wu_g, Wm_p, Wu_p, 1,
                                   OFF_HB_G, OFF_HB_P, OFF_HA_G, OFF_HA_P);
    // layer 2: HA -> HB
    k_agg<<<512, 256, 0, stream>>>(obs, ws, OFF_HA_G, OFF_HA_P);
    k_mlp<<<256, 256, 0, stream>>>(ws, Wm_g, Wu_g, Wm_p, Wu_p, 2,
                                   OFF_HA_G, OFF_HA_P, OFF_HB_G, OFF_HB_P);

    k_hsum<<<8, 256, 0, stream>>>(ws);
    k_pool<<<1, 256, 0, stream>>>(Wpg, Wpp, Wro, bro, ws);
    k_out<<<8, 256, 0, stream>>>(Wro, ws, out);
}

// Round 8
// 118.969 us; speedup vs baseline: 1.3047x; 1.1162x over previous
//
#include <hip/hip_runtime.h>

#define NF 64

// ws float offsets
#define OFF_NORMG   0          // 2048
#define OFF_NORMP   2048       // 2048
#define OFF_SG      4096       // 2048
#define OFF_SP      6144       // 2048
#define OFF_MAXG    8192       // 1
#define OFF_MAXP    8193       // 1
#define OFF_U       8194       // 128
#define OFF_HSUMG   8322       // 256
#define OFF_HSUMP   8578       // 256
#define OFF_C1      8834       // 4
#define OFF_NPG     9216       // 16384
#define OFF_NPP     25600      // 16384
#define OFF_HA_G    41984      // 131072
#define OFF_HA_P    173056
#define OFF_HB_G    304128
#define OFF_HB_P    435200
#define OFF_EG      566272
#define OFF_EP      697344
#define OFF_OBST    828416     // 1048576
#define OFF_AGG     1900544    // [side][2048][64] = 262144
#define OFF_AFRAG   2162688    // 2M ushorts = 1048576 floats (A frags, both sides)
#define OFF_HFRAG   3211264    // 4 x 262144 ushorts = 524288 floats (h frags hi/lo x side)

typedef __attribute__((ext_vector_type(8))) short bf16x8;
typedef __attribute__((ext_vector_type(4))) float f32x4;

static __device__ __forceinline__ float wave_sum(float v) {
    for (int off = 32; off; off >>= 1) v += __shfl_down(v, off, 64);
    return v;
}
static __device__ __forceinline__ float wave_max(float v) {
    for (int off = 32; off; off >>= 1) v = fmaxf(v, __shfl_down(v, off, 64));
    return v;
}
static __device__ __forceinline__ unsigned short f2bf(float x) {   // RNE bf16
    unsigned u = __float_as_uint(x);
    return (unsigned short)((u + 0x7FFFu + ((u >> 16) & 1u)) >> 16);
}
// store h element into B-frag layout (hi/lo): frag k-map == A-frag k-map
static __device__ __forceinline__ void store_hfrag(float* ws, int sideS, int lr, int f, float h) {
    int k = lr & 511, b = lr >> 9;
    int ft = f >> 4, ks = k >> 5;
    int lane2 = (f & 15) | (((k >> 3) & 3) << 4);
    int ii = k & 7;
    unsigned short hi = f2bf(h);
    float hif = __uint_as_float((unsigned)hi << 16);
    unsigned short lo = f2bf(h - hif);
    unsigned short* hf = (unsigned short*)(ws + OFF_HFRAG);
    size_t fidx = ((((size_t)b * 4 + ft) * 16 + ks) * 64 + lane2) * 8 + ii;
    hf[(size_t)sideS * 2 * 262144 + fidx] = hi;
    hf[((size_t)sideS * 2 + 1) * 262144 + fidx] = lo;
}

// ---------------- K1: transpose obs -> obsT, partial row/col nonzero counts ----------------
__global__ __launch_bounds__(256) void k_prep(const float* __restrict__ obs,
                                              float* __restrict__ ws) {
    __shared__ float tile[64][65];
    __shared__ float cc[4][64];
    int b = blockIdx.y, t = threadIdx.x;
    int tg = blockIdx.x >> 3, tp = blockIdx.x & 7;
    int g0 = tg * 64, p0 = tp * 64;
    int c = t & 63, r0 = t >> 6;
    const float* src = obs + ((size_t)b * 512 + g0) * 512 + p0;
    float colcnt = 0.f;
#pragma unroll
    for (int i = 0; i < 16; ++i) {
        int r = r0 + 4 * i;
        float v = src[(size_t)r * 512 + c];
        tile[r][c] = v;
        float nz = (v != 0.f) ? 1.f : 0.f;
        colcnt += nz;
        nz = wave_sum(nz);
        if (c == 0) ws[OFF_NPG + tp * 2048 + b * 512 + g0 + r] = nz;
    }
    cc[r0][c] = colcnt;
    __syncthreads();
    if (r0 == 0)
        ws[OFF_NPP + tg * 2048 + b * 512 + p0 + c] =
            cc[0][c] + cc[1][c] + cc[2][c] + cc[3][c];
    float* dst = ws + OFF_OBST + ((size_t)b * 512 + p0) * 512 + g0;
#pragma unroll
    for (int i = 0; i < 16; ++i) {
        int pr = r0 + 4 * i;
        dst[(size_t)pr * 512 + c] = tile[c][pr];
    }
}

// ---------------- K1b: reduce partials -> norms ----------------
__global__ __launch_bounds__(256) void k_norm(float* __restrict__ ws) {
    int idx = blockIdx.x * 256 + threadIdx.x;   // 0..4095
    int side = idx >> 11, lr = idx & 2047;
    const float* part = ws + (side ? OFF_NPP : OFF_NPG) + lr;
    float s = 0.f;
#pragma unroll
    for (int j = 0; j < 8; ++j) s += part[j * 2048];
    ws[(side ? OFF_NORMP : OFF_NORMG) + lr] = s;
}

// ---------------- K2: S sums; block 1024 does norm-maxes + U precompute ----------------
__global__ __launch_bounds__(256) void k_s(const float* __restrict__ obs,
                                           float* __restrict__ ws,
                                           const float* __restrict__ Wee_g,
                                           const float* __restrict__ Wef_g,
                                           const float* __restrict__ Wee_p,
                                           const float* __restrict__ Wef_p) {
    int bid = blockIdx.x;
    if (bid == 1024) {
        __shared__ float redg[4], redp[4];
        int t = threadIdx.x, lane = t & 63, w = t >> 6;
        float mg = 0.f, mp = 0.f;
        for (int k = t; k < 2048; k += 256) {
            mg = fmaxf(mg, ws[OFF_NORMG + k]);
            mp = fmaxf(mp, ws[OFF_NORMP + k]);
        }
        mg = wave_max(mg);
        mp = wave_max(mp);
        if (lane == 0) { redg[w] = mg; redp[w] = mp; }
        __syncthreads();
        if (t == 0) {
            ws[OFF_MAXG] = fmaxf(fmaxf(redg[0], redg[1]), fmaxf(redg[2], redg[3]));
            ws[OFF_MAXP] = fmaxf(fmaxf(redp[0], redp[1]), fmaxf(redp[2], redp[3]));
        }
        if (t < 128) {
            int side = t >> 6, f = t & 63;
            const float* Wee = side ? Wee_p : Wee_g;
            const float* Wef = side ? Wef_p : Wef_g;
            float u = 0.f;
#pragma unroll
            for (int e = 0; e < 63; ++e) u += fmaxf(Wee[e], 0.f) * Wef[e * 64 + f];
            ws[OFF_U + t] = u;
        }
        return;
    }
    int t = threadIdx.x, w = t >> 6, lane = t & 63;
    int row = bid * 4 + w;
    int side = row >> 11;
    int lr = row & 2047;
    int b = lr >> 9;
    const float* arow = side ? (ws + OFF_OBST + (size_t)lr * 512)
                             : (obs + (size_t)lr * 512);
    const float* wnorm = ws + (side ? OFF_NORMG : OFF_NORMP) + b * 512;
    float s = 0.f;
#pragma unroll
    for (int k = 0; k < 8; ++k) {
        int p = lane + 64 * k;
        float v = arow[p];
        if (v != 0.f) s += wnorm[p];
    }
    s = wave_sum(s) * (1.f / 512.f);
    if (lane == 0) ws[(side ? OFF_SP : OFF_SG) + lr] = s;
}

// ---------------- K2b: pack obs/obsT -> bf16 A-frags ----------------
// A-frag map: lane holds A[rt*16 + (lane&15)][ks*32 + ((lane>>4)<<3) + i], i=0..7
__global__ __launch_bounds__(256) void k_pack(const float* __restrict__ obs,
                                              float* __restrict__ ws) {
    int bid = blockIdx.x;              // side*128 + rt
    int side = bid >> 7, rt = bid & 127;
    int t = threadIdx.x, lane = t & 63, w = t >> 6;
    const float* src = side ? (ws + OFF_OBST) : obs;
    unsigned short* dst = (unsigned short*)(ws + OFF_AFRAG) + (size_t)side * 1048576;
    int row = rt * 16 + (lane & 15);
    int kbase = (lane >> 4) << 3;
#pragma unroll
    for (int q = 0; q < 4; ++q) {
        int ks = w * 4 + q;
        const float* s = src + (size_t)row * 512 + ks * 32 + kbase;
        bf16x8 o;
#pragma unroll
        for (int i = 0; i < 8; ++i) o[i] = (short)f2bf(s[i]);
        *(bf16x8*)(dst + ((size_t)(rt * 16 + ks) * 64 + lane) * 8) = o;
    }
}

// ---------------- K3: init h and e; also emit h frags ----------------
__global__ __launch_bounds__(256) void k_init(const float* __restrict__ Wi_g,
                                              const float* __restrict__ Wi_p,
                                              const float* __restrict__ Wef_g,
                                              const float* __restrict__ Wef_p,
                                              float* __restrict__ ws) {
    int idx = blockIdx.x * 256 + threadIdx.x;  // 0..262143
    int row = idx >> 6, f = idx & 63;
    int side = row >> 11, lr = row & 2047;
    float norm = ws[(side ? OFF_NORMP : OFF_NORMG) + lr];
    float nf1 = norm > 0.f ? norm : 1.f;
    float nf = norm * (1.f / 512.f);
    const float* Wi = side ? Wi_p : Wi_g;
    float h = fmaxf(nf * Wi[f], 0.f);
    ws[(side ? OFF_HA_P : OFF_HA_G) + (size_t)lr * 64 + f] = h;
    store_hfrag(ws, side, lr, f, h);
    float A = ws[(side ? OFF_SP : OFF_SG) + lr] / nf1;
    float maxnf = fmaxf(ws[side ? OFF_MAXP : OFF_MAXG], 1.f);
    float C = norm / maxnf;
    float U = ws[OFF_U + side * 64 + f];
    const float* Wef = side ? Wef_p : Wef_g;
    float e = fmaxf(A * U + C * Wef[63 * 64 + f], 0.f);
    ws[(side ? OFF_EP : OFF_EG) + (size_t)lr * 64 + f] = e;
}

// ---------------- K4a: MFMA aggregation. 256 blocks x 256 threads ----------------
// agg[side][row][f] = (A_side @ h_opp) / nf1 ; A exact bf16, h = hi + lo.
__global__ __launch_bounds__(256) void k_agg(float* __restrict__ ws) {
    int bid = blockIdx.x;              // side*128 + rt
    int side = bid >> 7, rt = bid & 127;
    int b = rt >> 5;
    int t = threadIdx.x, lane = t & 63;
    int ft = __builtin_amdgcn_readfirstlane(t >> 6);
    const unsigned short* af = (const unsigned short*)(ws + OFF_AFRAG) + (size_t)side * 1048576;
    const unsigned short* hfh = (const unsigned short*)(ws + OFF_HFRAG)
                                + (size_t)(1 - side) * 2 * 262144;
    const unsigned short* hfl = hfh + 262144;
    f32x4 acch = {0.f, 0.f, 0.f, 0.f};
    f32x4 accl = {0.f, 0.f, 0.f, 0.f};
#pragma unroll
    for (int ks = 0; ks < 16; ++ks) {
        bf16x8 a = *(const bf16x8*)(af + ((size_t)(rt * 16 + ks) * 64 + lane) * 8);
        size_t bi = ((((size_t)b * 4 + ft) * 16 + ks) * 64 + lane) * 8;
        bf16x8 bh = *(const bf16x8*)(hfh + bi);
        bf16x8 bl = *(const bf16x8*)(hfl + bi);
        acch = __builtin_amdgcn_mfma_f32_16x16x32_bf16(a, bh, acch, 0, 0, 0);
        accl = __builtin_amdgcn_mfma_f32_16x16x32_bf16(a, bl, accl, 0, 0, 0);
    }
    const float* nrm = ws + (side ? OFF_NORMP : OFF_NORMG) + rt * 16;
    float* aggout = ws + OFF_AGG + (size_t)side * 131072
                    + (size_t)(rt * 16) * 64 + ft * 16 + (lane & 15);
#pragma unroll
    for (int j = 0; j < 4; ++j) {
        int r = ((lane >> 4) << 2) + j;
        float v = (acch[j] + accl[j]) / fmaxf(nrm[r], 1.f);
        aggout[(size_t)r * 64] = v;
    }
}

// ---------------- K4b: MLP (msg + upd). 256 blocks x 256 threads ----------------
__global__ __launch_bounds__(256) void k_mlp(float* __restrict__ ws,
                                             const float* __restrict__ Wmsg_g,
                                             const float* __restrict__ Wupd_g,
                                             const float* __restrict__ Wmsg_p,
                                             const float* __restrict__ Wupd_p,
                                             int layer, int hin_g, int hin_p,
                                             int hout_g, int hout_p) {
    __shared__ float agglds[16][NF];
    __shared__ float mlds[16][NF];
    int bid = blockIdx.x, side = bid >> 7, tile = bid & 127;
    int R0 = tile * 16;
    int t = threadIdx.x, lane = t & 63;

    {   // stage agg tile (already normalized)
        int rr = t >> 6;
#pragma unroll
        for (int q = 0; q < 4; ++q) {
            int r = q * 4 + rr;
            agglds[r][lane] = ws[OFF_AGG + (size_t)side * 131072 + (size_t)(R0 + r) * 64 + lane];
        }
    }
    __syncthreads();

    int w = __builtin_amdgcn_readfirstlane(t >> 6);   // rows w*4 .. w*4+3
    const float* Wm = (side ? Wmsg_p : Wmsg_g) + layer * 8192;
    const float* Wu = (side ? Wupd_p : Wupd_g) + layer * 8192;
    const float* e0 = ws + (side ? OFF_EP : OFF_EG) + (size_t)R0 * 64 + w * 4 * 64;
    const float* h0 = ws + (side ? hin_p : hin_g) + (size_t)R0 * 64 + w * 4 * 64;
    float* hout = ws + (side ? hout_p : hout_g) + (size_t)R0 * 64 + w * 4 * 64;

    // ---- msg = relu([agg, e] @ Wm) ----
    float m0 = 0.f, m1 = 0.f, m2 = 0.f, m3 = 0.f;
#pragma unroll 4
    for (int k4 = 0; k4 < 16; ++k4) {
        float4 a0 = *(const float4*)&agglds[w * 4 + 0][k4 * 4];
        float4 a1 = *(const float4*)&agglds[w * 4 + 1][k4 * 4];
        float4 a2 = *(const float4*)&agglds[w * 4 + 2][k4 * 4];
        float4 a3 = *(const float4*)&agglds[w * 4 + 3][k4 * 4];
#pragma unroll
        for (int j = 0; j < 4; ++j) {
            float wv = Wm[(k4 * 4 + j) * 64 + lane];
            m0 = fmaf(((const float*)&a0)[j], wv, m0);
            m1 = fmaf(((const float*)&a1)[j], wv, m1);
            m2 = fmaf(((const float*)&a2)[j], wv, m2);
            m3 = fmaf(((const float*)&a3)[j], wv, m3);
        }
    }
#pragma unroll 4
    for (int k4 = 0; k4 < 16; ++k4) {
#pragma unroll
        for (int j = 0; j < 4; ++j) {
            int k = k4 * 4 + j;
            float wv = Wm[(64 + k) * 64 + lane];
            m0 = fmaf(e0[k], wv, m0);
            m1 = fmaf(e0[64 + k], wv, m1);
            m2 = fmaf(e0[128 + k], wv, m2);
            m3 = fmaf(e0[192 + k], wv, m3);
        }
    }
    mlds[w * 4 + 0][lane] = fmaxf(m0, 0.f);
    mlds[w * 4 + 1][lane] = fmaxf(m1, 0.f);
    mlds[w * 4 + 2][lane] = fmaxf(m2, 0.f);
    mlds[w * 4 + 3][lane] = fmaxf(m3, 0.f);
    __syncthreads();

    // ---- h_new = relu([h, m] @ Wu) ----
    float h0a = 0.f, h1a = 0.f, h2a = 0.f, h3a = 0.f;
#pragma unroll 4
    for (int k4 = 0; k4 < 16; ++k4) {
#pragma unroll
        for (int j = 0; j < 4; ++j) {
            int k = k4 * 4 + j;
            float wv = Wu[k * 64 + lane];
            h0a = fmaf(h0[k], wv, h0a);
            h1a = fmaf(h0[64 + k], wv, h1a);
            h2a = fmaf(h0[128 + k], wv, h2a);
            h3a = fmaf(h0[192 + k], wv, h3a);
        }
    }
#pragma unroll 4
    for (int k4 = 0; k4 < 16; ++k4) {
        float4 q0 = *(const float4*)&mlds[w * 4 + 0][k4 * 4];
        float4 q1 = *(const float4*)&mlds[w * 4 + 1][k4 * 4];
        float4 q2 = *(const float4*)&mlds[w * 4 + 2][k4 * 4];
        float4 q3 = *(const float4*)&mlds[w * 4 + 3][k4 * 4];
#pragma unroll
        for (int j = 0; j < 4; ++j) {
            float wv = Wu[(64 + k4 * 4 + j) * 64 + lane];
            h0a = fmaf(((const float*)&q0)[j], wv, h0a);
            h1a = fmaf(((const float*)&q1)[j], wv, h1a);
            h2a = fmaf(((const float*)&q2)[j], wv, h2a);
            h3a = fmaf(((const float*)&q3)[j], wv, h3a);
        }
    }
    h0a = fmaxf(h0a, 0.f); h1a = fmaxf(h1a, 0.f);
    h2a = fmaxf(h2a, 0.f); h3a = fmaxf(h3a, 0.f);
    hout[lane]       = h0a;
    hout[64 + lane]  = h1a;
    hout[128 + lane] = h2a;
    hout[192 + lane] = h3a;
    int lr = R0 + w * 4;
    store_hfrag(ws, side, lr + 0, lane, h0a);
    store_hfrag(ws, side, lr + 1, lane, h1a);
    store_hfrag(ws, side, lr + 2, lane, h2a);
    store_hfrag(ws, side, lr + 3, lane, h3a);
}

// ---------------- K4c: column sums of final h ----------------
__global__ __launch_bounds__(256) void k_hsum(float* __restrict__ ws) {
    __shared__ float red[4][NF];
    int bid = blockIdx.x, side = bid >> 2, b = bid & 3;
    int t = threadIdx.x, f = t & 63, w = t >> 6;
    const float* h = ws + (side ? OFF_HB_P : OFF_HB_G) + (size_t)b * 32768;
    float s = 0.f;
    for (int r = w; r < 512; r += 4) s += h[(size_t)r * 64 + f];
    red[w][f] = s;
    __syncthreads();
    if (w == 0)
        ws[(side ? OFF_HSUMP : OFF_HSUMG) + b * 64 + f] =
            red[0][f] + red[1][f] + red[2][f] + red[3][f];
}

// ---------------- K5: pooled readout constant c1[b] ----------------
__global__ __launch_bounds__(256) void k_pool(const float* __restrict__ Wpg,
                                              const float* __restrict__ Wpp,
                                              const float* __restrict__ Wro,
                                              const float* __restrict__ bro,
                                              float* __restrict__ ws) {
    int t = threadIdx.x;
    int b = t >> 6, f = t & 63;
    const float* hsg = ws + OFF_HSUMG + b * 64;
    const float* hsp = ws + OFF_HSUMP + b * 64;
    float vg = 0.f, vp = 0.f;
#pragma unroll
    for (int k = 0; k < 64; ++k) {
        vg += (hsg[k] * (1.f / 512.f)) * Wpg[k * 64 + f];
        vp += (hsp[k] * (1.f / 512.f)) * Wpp[k * 64 + f];
    }
    float hp = fmaxf(vg + vp, 0.f);
    float c = wave_sum(hp * Wro[f]);
    if (f == 0) ws[OFF_C1 + b] = c + bro[0];
}

// ---------------- K6: out[b,g] = c1[b] + h_g[b,g,:] . Wro[64:128] ----------------
__global__ __launch_bounds__(256) void k_out(const float* __restrict__ Wro,
                                             const float* __restrict__ ws,
                                             float* __restrict__ out) {
    int idx = blockIdx.x * 256 + threadIdx.x;
    int b = idx >> 9;
    const float4* hrow = (const float4*)(ws + OFF_HB_G + (size_t)idx * 64);
    float s = 0.f;
#pragma unroll
    for (int k4 = 0; k4 < 16; ++k4) {
        float4 h4 = hrow[k4];
        s += h4.x * Wro[64 + k4 * 4 + 0];
        s += h4.y * Wro[64 + k4 * 4 + 1];
        s += h4.z * Wro[64 + k4 * 4 + 2];
        s += h4.w * Wro[64 + k4 * 4 + 3];
    }
    out[idx] = ws[OFF_C1 + b] + s;
}

extern "C" void kernel_launch(void* const* d_in, const int* in_sizes, int n_in,
                              void* d_out, int out_size, void* d_ws, size_t ws_size,
                              hipStream_t stream) {
    const float* obs   = (const float*)d_in[0];
    const float* Wi_g  = (const float*)d_in[1];
    const float* Wi_p  = (const float*)d_in[2];
    const float* Wee_g = (const float*)d_in[3];
    const float* Wef_g = (const float*)d_in[4];
    const float* Wee_p = (const float*)d_in[5];
    const float* Wef_p = (const float*)d_in[6];
    const float* Wm_g  = (const float*)d_in[7];
    const float* Wu_g  = (const float*)d_in[8];
    const float* Wm_p  = (const float*)d_in[9];
    const float* Wu_p  = (const float*)d_in[10];
    const float* Wpg   = (const float*)d_in[11];
    const float* Wpp   = (const float*)d_in[12];
    const float* Wro   = (const float*)d_in[13];
    const float* bro   = (const float*)d_in[14];
    float* ws  = (float*)d_ws;
    float* out = (float*)d_out;

    k_prep<<<dim3(64, 4), 256, 0, stream>>>(obs, ws);
    k_norm<<<16, 256, 0, stream>>>(ws);
    k_s<<<1025, 256, 0, stream>>>(obs, ws, Wee_g, Wef_g, Wee_p, Wef_p);
    k_pack<<<256, 256, 0, stream>>>(obs, ws);
    k_init<<<1024, 256, 0, stream>>>(Wi_g, Wi_p, Wef_g, Wef_p, ws);

    // layer 0: HA -> HB
    k_agg<<<256, 256, 0, stream>>>(ws);
    k_mlp<<<256, 256, 0, stream>>>(ws, Wm_g, Wu_g, Wm_p, Wu_p, 0,
                                   OFF_HA_G, OFF_HA_P, OFF_HB_G, OFF_HB_P);
    // layer 1: HB -> HA
    k_agg<<<256, 256, 0, stream>>>(ws);
    k_mlp<<<256, 256, 0, stream>>>(ws, Wm_g, Wu_g, Wm_p, Wu_p, 1,
                                   OFF_HB_G, OFF_HB_P, OFF_HA_G, OFF_HA_P);
    // layer 2: HA -> HB
    k_agg<<<256, 256, 0, stream>>>(ws);
    k_mlp<<<256, 256, 0, stream>>>(ws, Wm_g, Wu_g, Wm_p, Wu_p, 2,
                                   OFF_HA_G, OFF_HA_P, OFF_HB_G, OFF_HB_P);

    k_hsum<<<8, 256, 0, stream>>>(ws);
    k_pool<<<1, 256, 0, stream>>>(Wpg, Wpp, Wro, bro, ws);
    k_out<<<8, 256, 0, stream>>>(Wro, ws, out);
}